// Round 15
// baseline (226.248 us; speedup 1.0000x reference)
//
#include <hip/hip_runtime.h>
#include <stdint.h>

#define Bz 4
#define Tz 2048
#define Cz 1024
#define NHz 16
#define DHz 64
#define Mz (Bz*Tz)

typedef unsigned short u16;
typedef __attribute__((ext_vector_type(8))) short short8;
typedef __attribute__((ext_vector_type(8))) unsigned short ushort8v;
typedef __attribute__((ext_vector_type(4))) unsigned short u16x4;
typedef __attribute__((ext_vector_type(4))) float f32x4;
typedef __attribute__((ext_vector_type(2))) unsigned int uint2v;

__device__ __forceinline__ float bf2f(u16 u){
  union { unsigned int i; float f; } v; v.i = ((unsigned int)u) << 16; return v.f;
}
__device__ __forceinline__ u16 f2bf(float f){
  union { float f; unsigned int i; } v; v.f = f;
  unsigned int r = v.i + 0x7FFFu + ((v.i >> 16) & 1u);
  return (u16)(r >> 16);
}

// ---------------- fused pre-pass ----------------
__global__ void k_prep(const float* __restrict__ x,     u16* __restrict__ xb,
                       const float* __restrict__ Wqkv,  u16* __restrict__ wqt,
                       const float* __restrict__ Wproj, u16* __restrict__ wpt,
                       float* __restrict__ cosT, float* __restrict__ sinT){
  __shared__ float tile[32][33];
  const int blk = blockIdx.x;
  const int tid = threadIdx.x;
  if (blk < 8192){
    int i = blk*256 + tid;
    float4 v = ((const float4*)x)[i];
    u16x4 o;
    o[0] = f2bf(v.x); o[1] = f2bf(v.y); o[2] = f2bf(v.z); o[3] = f2bf(v.w);
    *(u16x4*)(xb + (size_t)i*4) = o;
  } else if (blk < 12288){
    const float* W; u16* Wt; int K, N, bx, by;
    if (blk < 11264){ int b2 = blk - 8192;  W = Wqkv;  Wt = wqt; K = 1024; N = 3072; bx = b2 % 96; by = b2 / 96; }
    else            { int b2 = blk - 11264; W = Wproj; Wt = wpt; K = 1024; N = 1024; bx = b2 % 32; by = b2 / 32; }
    const int n0 = bx*32, k0 = by*32;
    const int tx = tid & 31, ty = tid >> 5;
    #pragma unroll
    for (int i = 0; i < 32; i += 8)
      tile[ty+i][tx] = W[(size_t)(k0+ty+i)*N + n0 + tx];
    __syncthreads();
    #pragma unroll
    for (int i = 0; i < 32; i += 8)
      Wt[(size_t)(n0+ty+i)*K + k0 + tx] = f2bf(tile[tx][ty+i]);
  } else {
    int idx = (blk - 12288)*256 + tid;      // 2048*32 entries
    int t = idx >> 5, i = idx & 31;
    float theta = exp2f(-(float)i * (13.287712379549449f / 32.0f)); // 10000^(-i/32)
    float ang = (float)t * theta;
    cosT[idx] = cosf(ang);
    sinT[idx] = sinf(ang);
  }
}

// ---------------- GEMM: 128x128, BK=64, 4 waves of 64x64, double-buffered ----------------
#define GLDS(src, dstE) __builtin_amdgcn_global_load_lds( \
    (const __attribute__((address_space(1))) unsigned int*)(src), \
    (__attribute__((address_space(3))) unsigned int*)((u16*)lds + (dstE)), 16, 0, 0)

template<int Nn, int Kk, bool ROPE>
__global__ __launch_bounds__(256, 4) void k_gemmdb(const u16* __restrict__ A, const u16* __restrict__ Bt,
                        void* __restrict__ Cout, u16* __restrict__ vTout,
                        const float* __restrict__ cosT, const float* __restrict__ sinT){
  __shared__ u16 lds[2][16384];           // [buf][ A 128x64 | B 128x64 ]  = 64 KB
  constexpr int NT = Kk/64;
  const int bm = blockIdx.x, bn = blockIdx.y;
  const int tid = threadIdx.x, lane = tid & 63, w = tid >> 6;
  const int wm = (w >> 1)*64, wn = (w & 1)*64;
  const int g = lane >> 4, r = lane & 15;

  const int srow8 = lane >> 3;
  const int sslot = (lane & 7) ^ srow8;   // pre-swizzled source slot (involution)
  const u16* asrc = A  + (size_t)(bm*128 + w*32 + srow8)*Kk + sslot*8;
  const u16* bsrc = Bt + (size_t)(bn*128 + w*32 + srow8)*Kk + sslot*8;
  const int dA = w*2048 + lane*8;
  const int dB = 8192 + w*2048 + lane*8;

  int a_off[4][2], b_off[4][2];
  #pragma unroll
  for (int i = 0; i < 4; ++i)
    #pragma unroll
    for (int kc = 0; kc < 2; ++kc){
      int row = wm + i*16 + r;
      a_off[i][kc] = (row*128 + kc*64 + g*16) ^ ((r & 7) << 4);
      int rowb = wn + i*16 + r;
      b_off[i][kc] = 16384 + ((rowb*128 + kc*64 + g*16) ^ ((r & 7) << 4));
    }

  f32x4 acc[4][4] = {};

#define STG(t, bi) do{ \
    const size_t ko_ = (size_t)(t)*64; \
    const int be_ = (bi)*16384; \
    GLDS(asrc + ko_,                 be_ + dA);        \
    GLDS(asrc + ko_ +  8*(size_t)Kk, be_ + dA + 512);  \
    GLDS(asrc + ko_ + 16*(size_t)Kk, be_ + dA + 1024); \
    GLDS(asrc + ko_ + 24*(size_t)Kk, be_ + dA + 1536); \
    GLDS(bsrc + ko_,                 be_ + dB);        \
    GLDS(bsrc + ko_ +  8*(size_t)Kk, be_ + dB + 512);  \
    GLDS(bsrc + ko_ + 16*(size_t)Kk, be_ + dB + 1024); \
    GLDS(bsrc + ko_ + 24*(size_t)Kk, be_ + dB + 1536); \
  }while(0)

  STG(0, 0);
  asm volatile("s_waitcnt vmcnt(0)" ::: "memory");
  __builtin_amdgcn_s_barrier();

  int buf = 0;
  #pragma unroll 1
  for (int t = 0; t < NT; ++t){
    if (t + 1 < NT) STG(t+1, buf^1);
    const char* Lb = (const char*)lds + buf*32768;
    short8 af[4][2], bf[4][2];
    #pragma unroll
    for (int i = 0; i < 4; ++i)
      #pragma unroll
      for (int kc = 0; kc < 2; ++kc){
        af[i][kc] = *(const short8*)(Lb + a_off[i][kc]);
        bf[i][kc] = *(const short8*)(Lb + b_off[i][kc]);
      }
    __builtin_amdgcn_s_setprio(1);
    #pragma unroll
    for (int i = 0; i < 4; ++i)
      #pragma unroll
      for (int j = 0; j < 4; ++j){
        acc[i][j] = __builtin_amdgcn_mfma_f32_16x16x32_bf16(af[i][0], bf[j][0], acc[i][j], 0,0,0);
        acc[i][j] = __builtin_amdgcn_mfma_f32_16x16x32_bf16(af[i][1], bf[j][1], acc[i][j], 0,0,0);
      }
    __builtin_amdgcn_s_setprio(0);
    if (t + 1 < NT){
      asm volatile("s_waitcnt vmcnt(0)" ::: "memory");
      __builtin_amdgcn_s_barrier();
      buf ^= 1;
    }
  }
#undef STG

  // ---------------- epilogue ----------------
  const int nbase = bn*128 + wn;
  if (ROPE && nbase >= 2048){
    const int b = bm >> 4;
    const int h = (nbase >> 6) & 15;
    #pragma unroll
    for (int ri = 0; ri < 4; ++ri){
      const int m0 = bm*128 + wm + ri*16 + 4*g;
      const int t0 = m0 & (Tz-1);
      #pragma unroll
      for (int cj = 0; cj < 4; ++cj){
        const int d = cj*16 + r;
        u16x4 o;
        #pragma unroll
        for (int jj = 0; jj < 4; ++jj) o[jj] = f2bf(acc[ri][cj][jj]);
        *(u16x4*)(vTout + ((size_t)((b*16 + h)*64 + d))*2048 + t0) = o;
      }
    }
  } else if (ROPE){
    const float qs = (nbase < 1024) ? 0.18033688011112042f : 1.0f;  // 0.125*log2e on q
    #pragma unroll
    for (int ri = 0; ri < 4; ++ri)
      #pragma unroll
      for (int jj = 0; jj < 4; ++jj){
        const int m = bm*128 + wm + ri*16 + 4*g + jj;
        const int t = m & (Tz-1);
        #pragma unroll
        for (int cj = 0; cj < 2; ++cj){
          const int ch = cj*16 + r;
          float cv = cosT[t*32 + ch];
          float sv = sinT[t*32 + ch];
          float lo = acc[ri][cj][jj], hi = acc[ri][cj+2][jj];
          ((u16*)Cout)[(size_t)m*Nn + nbase + ch]      = f2bf((lo*cv - hi*sv)*qs);
          ((u16*)Cout)[(size_t)m*Nn + nbase + ch + 32] = f2bf((hi*cv + lo*sv)*qs);
        }
      }
  } else {
    #pragma unroll
    for (int ri = 0; ri < 4; ++ri)
      #pragma unroll
      for (int cj = 0; cj < 4; ++cj)
        #pragma unroll
        for (int jj = 0; jj < 4; ++jj){
          const size_t m = bm*128 + wm + ri*16 + 4*g + jj;
          const size_t n = (size_t)nbase + cj*16 + r;
          ((float*)Cout)[m*Nn + n] = acc[ri][cj][jj];
        }
  }
}

// ---------------- flash attention v9: 32 q/wave x 8 waves ----------------
// 512 threads, 256 q-rows/block, grid (64 bh, 8 qt2) heavy-first.
// Each K/V frag ds_read feeds TWO q-subtiles: LDS cyc/subtile 240 -> 144
// (attn is LDS-instruction-throughput-bound; v7 model 54us == measured 55).
// 16 waves/CU (2 blocks x 69.6KB dynamic LDS). v6-proven inner math.
__global__ __launch_bounds__(512, 4) void k_attn3(const u16* __restrict__ qkv,
                                                  const u16* __restrict__ vT,
                                                  u16* __restrict__ att){
  extern __shared__ u16 smem[];   // K 2x4096 | V 2x4096 | P 8x32x72  = 69632 B
  u16* K_lds = smem;
  u16* V_lds = smem + 8192;
  u16* P_lds = smem + 16384;

  const int bh = blockIdx.x;
  const int b = bh >> 4, h = bh & 15;
  const int qt2 = 7 - blockIdx.y;      // heavy blocks first
  const int tid = threadIdx.x;
  const int w = tid >> 6;              // 0..7
  const int lane = tid & 63;
  const int g = lane >> 4;
  const int ql = lane & 15;
  u16* Pw = P_lds + w*2304;            // 32 rows x 72 u16 (144 B stride)

  const int srow  = lane >> 3;
  const int sslot = (lane & 7) ^ srow;
  const u16* ksrc = qkv + ((size_t)(b*Tz + 8*w + srow))*3072 + 1024 + h*64 + sslot*8;
  const u16* vsrc = vT  + ((size_t)bh*64 + 8*w + srow)*2048 + sslot*8;
  u16* kdst = K_lds + w*512 + lane*8;
  u16* vdst = V_lds + w*512 + lane*8;

  int fofs[4][2];
  #pragma unroll
  for (int t = 0; t < 4; ++t){
    int row = 16*t + ql;
    fofs[t][0] = (row*128 + 16*g)      ^ ((row & 7) << 4);
    fofs[t][1] = (row*128 + 64 + 16*g) ^ ((row & 7) << 4);
  }

#define STG_KV(kt_, bi_) do{ \
    __builtin_amdgcn_global_load_lds( \
      (const __attribute__((address_space(1))) unsigned int*)(ksrc + (size_t)(kt_)*64*3072), \
      (__attribute__((address_space(3))) unsigned int*)(kdst + (bi_)*4096), 16, 0, 0); \
    __builtin_amdgcn_global_load_lds( \
      (const __attribute__((address_space(1))) unsigned int*)(vsrc + (kt_)*64), \
      (__attribute__((address_space(3))) unsigned int*)(vdst + (bi_)*4096), 16, 0, 0); \
  }while(0)

  const int qr0w = qt2*256 + w*32;     // wave's 32 q-rows
  const int nt = (qt2 + 1)*4;

  const u16* qsrcA = qkv + (size_t)(b*Tz + qr0w + ql)*3072 + h*64;
  const u16* qsrcB = qsrcA + 16*3072;
  short8 qfA0 = *(const short8*)(qsrcA + g*8);
  short8 qfA1 = *(const short8*)(qsrcA + 32 + g*8);
  short8 qfB0 = *(const short8*)(qsrcB + g*8);
  short8 qfB1 = *(const short8*)(qsrcB + 32 + g*8);

  f32x4 accA[4] = {{0,0,0,0},{0,0,0,0},{0,0,0,0},{0,0,0,0}};
  f32x4 accB[4] = {{0,0,0,0},{0,0,0,0},{0,0,0,0},{0,0,0,0}};
  float lrA = 0.0f, lrB = 0.0f;

  STG_KV(0, 0);
  __syncthreads();

  #pragma unroll 2
  for (int kt = 0; kt < nt; ++kt){
    const int buf = kt & 1;
    if (kt + 1 < nt) STG_KV(kt+1, buf^1);
    const char* Kb = (const char*)(K_lds + buf*4096);
    const char* Vb = (const char*)(V_lds + buf*4096);
    const int kv0 = kt*64;

    // QK^T for both subtiles, sharing each K-frag read
    f32x4 stA[4], stB[4];
    __builtin_amdgcn_s_setprio(1);
    #pragma unroll
    for (int t = 0; t < 4; ++t){
      short8 kf0 = *(const short8*)(Kb + fofs[t][0]);
      short8 kf1 = *(const short8*)(Kb + fofs[t][1]);
      f32x4 zA = {0,0,0,0};
      zA = __builtin_amdgcn_mfma_f32_16x16x32_bf16(kf0, qfA0, zA, 0, 0, 0);
      zA = __builtin_amdgcn_mfma_f32_16x16x32_bf16(kf1, qfA1, zA, 0, 0, 0);
      stA[t] = zA;
      f32x4 zB = {0,0,0,0};
      zB = __builtin_amdgcn_mfma_f32_16x16x32_bf16(kf0, qfB0, zB, 0, 0, 0);
      zB = __builtin_amdgcn_mfma_f32_16x16x32_bf16(kf1, qfB1, zB, 0, 0, 0);
      stB[t] = zB;
    }
    __builtin_amdgcn_s_setprio(0);

    // causal masks (wave-uniform branches)
    if (kv0 + 63 > qr0w){
      const int qg = qr0w + ql;
      #pragma unroll
      for (int t = 0; t < 4; ++t)
        #pragma unroll
        for (int j = 0; j < 4; ++j)
          if (kv0 + 16*t + 4*g + j > qg) stA[t][j] = -1e30f;
    }
    if (kv0 + 63 > qr0w + 16){
      const int qg = qr0w + 16 + ql;
      #pragma unroll
      for (int t = 0; t < 4; ++t)
        #pragma unroll
        for (int j = 0; j < 4; ++j)
          if (kv0 + 16*t + 4*g + j > qg) stB[t][j] = -1e30f;
    }

    // p = 2^s; per-lane partial row-sums; pack to P_lds (A rows 0-15, B rows 16-31)
    #pragma unroll
    for (int t = 0; t < 4; ++t){
      float a0, a1, a2, a3, b0, b1, b2, b3;
      asm("v_exp_f32 %0, %1" : "=v"(a0) : "v"(stA[t][0]));
      asm("v_exp_f32 %0, %1" : "=v"(a1) : "v"(stA[t][1]));
      asm("v_exp_f32 %0, %1" : "=v"(a2) : "v"(stA[t][2]));
      asm("v_exp_f32 %0, %1" : "=v"(a3) : "v"(stA[t][3]));
      asm("v_exp_f32 %0, %1" : "=v"(b0) : "v"(stB[t][0]));
      asm("v_exp_f32 %0, %1" : "=v"(b1) : "v"(stB[t][1]));
      asm("v_exp_f32 %0, %1" : "=v"(b2) : "v"(stB[t][2]));
      asm("v_exp_f32 %0, %1" : "=v"(b3) : "v"(stB[t][3]));
      lrA += (a0+a1)+(a2+a3);
      lrB += (b0+b1)+(b2+b3);
      unsigned int wa0, wa1, wb0, wb1;
      asm("v_cvt_pk_bf16_f32 %0, %1, %2" : "=v"(wa0) : "v"(a0), "v"(a1));
      asm("v_cvt_pk_bf16_f32 %0, %1, %2" : "=v"(wa1) : "v"(a2), "v"(a3));
      asm("v_cvt_pk_bf16_f32 %0, %1, %2" : "=v"(wb0) : "v"(b0), "v"(b1));
      asm("v_cvt_pk_bf16_f32 %0, %1, %2" : "=v"(wb1) : "v"(b2), "v"(b3));
      uint2v pva; pva[0] = wa0; pva[1] = wa1;
      uint2v pvb; pvb[0] = wb0; pvb[1] = wb1;
      *(uint2v*)((char*)Pw + ql*144 + (16*t + 4*g)*2) = pva;
      *(uint2v*)((char*)Pw + (16 + ql)*144 + (16*t + 4*g)*2) = pvb;
    }

    short8 pfA0 = *(const short8*)((char*)Pw + ql*144 + 16*g);
    short8 pfA1 = *(const short8*)((char*)Pw + ql*144 + 64 + 16*g);
    short8 pfB0 = *(const short8*)((char*)Pw + (16 + ql)*144 + 16*g);
    short8 pfB1 = *(const short8*)((char*)Pw + (16 + ql)*144 + 64 + 16*g);

    // PV for both subtiles, sharing each V-frag read
    __builtin_amdgcn_s_setprio(1);
    #pragma unroll
    for (int dt = 0; dt < 4; ++dt){
      short8 vf0 = *(const short8*)(Vb + fofs[dt][0]);
      short8 vf1 = *(const short8*)(Vb + fofs[dt][1]);
      accA[dt] = __builtin_amdgcn_mfma_f32_16x16x32_bf16(pfA0, vf0, accA[dt], 0, 0, 0);
      accA[dt] = __builtin_amdgcn_mfma_f32_16x16x32_bf16(pfA1, vf1, accA[dt], 0, 0, 0);
      accB[dt] = __builtin_amdgcn_mfma_f32_16x16x32_bf16(pfB0, vf0, accB[dt], 0, 0, 0);
      accB[dt] = __builtin_amdgcn_mfma_f32_16x16x32_bf16(pfB1, vf1, accB[dt], 0, 0, 0);
    }
    __builtin_amdgcn_s_setprio(0);
    __syncthreads();   // guards dbuf rotation (includes vmcnt drain)
  }
#undef STG_KV

  // denominator reduce once per q-tile
  lrA += __shfl_xor(lrA, 16); lrA += __shfl_xor(lrA, 32);
  lrB += __shfl_xor(lrB, 16); lrB += __shfl_xor(lrB, 32);
  float liA = 1.0f / lrA;
  float liB = 1.0f / lrB;
  float lA0 = __shfl(liA, 4*g+0), lA1 = __shfl(liA, 4*g+1);
  float lA2 = __shfl(liA, 4*g+2), lA3 = __shfl(liA, 4*g+3);
  float lB0 = __shfl(liB, 4*g+0), lB1 = __shfl(liB, 4*g+1);
  float lB2 = __shfl(liB, 4*g+2), lB3 = __shfl(liB, 4*g+3);
  #pragma unroll
  for (int dt = 0; dt < 4; ++dt){
    float ljA[4] = {lA0, lA1, lA2, lA3};
    float ljB[4] = {lB0, lB1, lB2, lB3};
    #pragma unroll
    for (int j = 0; j < 4; ++j){
      att[(size_t)(b*Tz + qr0w + 4*g + j)*Cz + h*64 + dt*16 + ql]      = f2bf(accA[dt][j]*ljA[j]);
      att[(size_t)(b*Tz + qr0w + 16 + 4*g + j)*Cz + h*64 + dt*16 + ql] = f2bf(accB[dt][j]*ljB[j]);
    }
  }
}

// ---------------- launcher ----------------

extern "C" void kernel_launch(void* const* d_in, const int* in_sizes, int n_in,
                              void* d_out, int out_size, void* d_ws, size_t ws_size,
                              hipStream_t stream){
  const float* x     = (const float*)d_in[0];
  const float* Wqkv  = (const float*)d_in[1];
  const float* Wproj = (const float*)d_in[2];
  float* out = (float*)d_out;
  char* ws = (char*)d_ws;

  u16*  xb   = (u16*)(ws);                      // x bf16; reused as attn output
  u16*  wqt  = (u16*)(ws + 16777216);
  u16*  wpt  = (u16*)(ws + 23068672);
  u16*  qkv  = (u16*)(ws + 25165824);           // q,k planes (v diverted to vT)
  u16*  vTr  = (u16*)(ws + 75497472);           // V^T [bh*64+d][2048]
  float* cosT = (float*)(ws + 92274688);
  float* sinT = (float*)(ws + 92536832);

  hipFuncSetAttribute(reinterpret_cast<const void*>(k_attn3),
                      hipFuncAttributeMaxDynamicSharedMemorySize, 69632);

  k_prep<<<12544, 256, 0, stream>>>(x, xb, Wqkv, wqt, Wproj, wpt, cosT, sinT);

  k_gemmdb<3072, 1024, true><<<dim3(Mz/128, 3072/128), 256, 0, stream>>>(
      xb, wqt, qkv, vTr, cosT, sinT);
  k_attn3<<<dim3(Bz*NHz, 8), 512, 69632, stream>>>(qkv, vTr, xb);
  k_gemmdb<1024, 1024, false><<<dim3(Mz/128, 1024/128), 256, 0, stream>>>(
      xb, wpt, out, nullptr, nullptr, nullptr);
}

// Round 16
// 153.240 us; speedup vs baseline: 1.4764x; 1.4764x over previous
//
#include <hip/hip_runtime.h>
#include <stdint.h>

#define Bz 4
#define Tz 2048
#define Cz 1024
#define NHz 16
#define DHz 64
#define Mz (Bz*Tz)

typedef unsigned short u16;
typedef __attribute__((ext_vector_type(8))) short short8;
typedef __attribute__((ext_vector_type(8))) unsigned short ushort8v;
typedef __attribute__((ext_vector_type(4))) unsigned short u16x4;
typedef __attribute__((ext_vector_type(4))) float f32x4;
typedef __attribute__((ext_vector_type(2))) unsigned int uint2v;

__device__ __forceinline__ float bf2f(u16 u){
  union { unsigned int i; float f; } v; v.i = ((unsigned int)u) << 16; return v.f;
}
__device__ __forceinline__ u16 f2bf(float f){
  union { float f; unsigned int i; } v; v.f = f;
  unsigned int r = v.i + 0x7FFFu + ((v.i >> 16) & 1u);
  return (u16)(r >> 16);
}

// ---------------- fused pre-pass ----------------
__global__ void k_prep(const float* __restrict__ x,     u16* __restrict__ xb,
                       const float* __restrict__ Wqkv,  u16* __restrict__ wqt,
                       const float* __restrict__ Wproj, u16* __restrict__ wpt,
                       float* __restrict__ cosT, float* __restrict__ sinT){
  __shared__ float tile[32][33];
  const int blk = blockIdx.x;
  const int tid = threadIdx.x;
  if (blk < 8192){
    int i = blk*256 + tid;
    float4 v = ((const float4*)x)[i];
    u16x4 o;
    o[0] = f2bf(v.x); o[1] = f2bf(v.y); o[2] = f2bf(v.z); o[3] = f2bf(v.w);
    *(u16x4*)(xb + (size_t)i*4) = o;
  } else if (blk < 12288){
    const float* W; u16* Wt; int K, N, bx, by;
    if (blk < 11264){ int b2 = blk - 8192;  W = Wqkv;  Wt = wqt; K = 1024; N = 3072; bx = b2 % 96; by = b2 / 96; }
    else            { int b2 = blk - 11264; W = Wproj; Wt = wpt; K = 1024; N = 1024; bx = b2 % 32; by = b2 / 32; }
    const int n0 = bx*32, k0 = by*32;
    const int tx = tid & 31, ty = tid >> 5;
    #pragma unroll
    for (int i = 0; i < 32; i += 8)
      tile[ty+i][tx] = W[(size_t)(k0+ty+i)*N + n0 + tx];
    __syncthreads();
    #pragma unroll
    for (int i = 0; i < 32; i += 8)
      Wt[(size_t)(n0+ty+i)*K + k0 + tx] = f2bf(tile[tx][ty+i]);
  } else {
    int idx = (blk - 12288)*256 + tid;      // 2048*32 entries
    int t = idx >> 5, i = idx & 31;
    float theta = exp2f(-(float)i * (13.287712379549449f / 32.0f)); // 10000^(-i/32)
    float ang = (float)t * theta;
    cosT[idx] = cosf(ang);
    sinT[idx] = sinf(ang);
  }
}

// ---------------- GEMM: 128x128, BK=64, 4 waves of 64x64, double-buffered ----------------
#define GLDS(src, dstE) __builtin_amdgcn_global_load_lds( \
    (const __attribute__((address_space(1))) unsigned int*)(src), \
    (__attribute__((address_space(3))) unsigned int*)((u16*)lds + (dstE)), 16, 0, 0)

template<int Nn, int Kk, bool ROPE>
__global__ __launch_bounds__(256, 4) void k_gemmdb(const u16* __restrict__ A, const u16* __restrict__ Bt,
                        void* __restrict__ Cout, u16* __restrict__ vTout,
                        const float* __restrict__ cosT, const float* __restrict__ sinT){
  __shared__ u16 lds[2][16384];           // [buf][ A 128x64 | B 128x64 ]  = 64 KB
  constexpr int NT = Kk/64;
  const int bm = blockIdx.x, bn = blockIdx.y;
  const int tid = threadIdx.x, lane = tid & 63, w = tid >> 6;
  const int wm = (w >> 1)*64, wn = (w & 1)*64;
  const int g = lane >> 4, r = lane & 15;

  const int srow8 = lane >> 3;
  const int sslot = (lane & 7) ^ srow8;   // pre-swizzled source slot (involution)
  const u16* asrc = A  + (size_t)(bm*128 + w*32 + srow8)*Kk + sslot*8;
  const u16* bsrc = Bt + (size_t)(bn*128 + w*32 + srow8)*Kk + sslot*8;
  const int dA = w*2048 + lane*8;
  const int dB = 8192 + w*2048 + lane*8;

  int a_off[4][2], b_off[4][2];
  #pragma unroll
  for (int i = 0; i < 4; ++i)
    #pragma unroll
    for (int kc = 0; kc < 2; ++kc){
      int row = wm + i*16 + r;
      a_off[i][kc] = (row*128 + kc*64 + g*16) ^ ((r & 7) << 4);
      int rowb = wn + i*16 + r;
      b_off[i][kc] = 16384 + ((rowb*128 + kc*64 + g*16) ^ ((r & 7) << 4));
    }

  f32x4 acc[4][4] = {};

#define STG(t, bi) do{ \
    const size_t ko_ = (size_t)(t)*64; \
    const int be_ = (bi)*16384; \
    GLDS(asrc + ko_,                 be_ + dA);        \
    GLDS(asrc + ko_ +  8*(size_t)Kk, be_ + dA + 512);  \
    GLDS(asrc + ko_ + 16*(size_t)Kk, be_ + dA + 1024); \
    GLDS(asrc + ko_ + 24*(size_t)Kk, be_ + dA + 1536); \
    GLDS(bsrc + ko_,                 be_ + dB);        \
    GLDS(bsrc + ko_ +  8*(size_t)Kk, be_ + dB + 512);  \
    GLDS(bsrc + ko_ + 16*(size_t)Kk, be_ + dB + 1024); \
    GLDS(bsrc + ko_ + 24*(size_t)Kk, be_ + dB + 1536); \
  }while(0)

  STG(0, 0);
  asm volatile("s_waitcnt vmcnt(0)" ::: "memory");
  __builtin_amdgcn_s_barrier();

  int buf = 0;
  #pragma unroll 1
  for (int t = 0; t < NT; ++t){
    if (t + 1 < NT) STG(t+1, buf^1);
    const char* Lb = (const char*)lds + buf*32768;
    short8 af[4][2], bf[4][2];
    #pragma unroll
    for (int i = 0; i < 4; ++i)
      #pragma unroll
      for (int kc = 0; kc < 2; ++kc){
        af[i][kc] = *(const short8*)(Lb + a_off[i][kc]);
        bf[i][kc] = *(const short8*)(Lb + b_off[i][kc]);
      }
    __builtin_amdgcn_s_setprio(1);
    #pragma unroll
    for (int i = 0; i < 4; ++i)
      #pragma unroll
      for (int j = 0; j < 4; ++j){
        acc[i][j] = __builtin_amdgcn_mfma_f32_16x16x32_bf16(af[i][0], bf[j][0], acc[i][j], 0,0,0);
        acc[i][j] = __builtin_amdgcn_mfma_f32_16x16x32_bf16(af[i][1], bf[j][1], acc[i][j], 0,0,0);
      }
    __builtin_amdgcn_s_setprio(0);
    if (t + 1 < NT){
      asm volatile("s_waitcnt vmcnt(0)" ::: "memory");
      __builtin_amdgcn_s_barrier();
      buf ^= 1;
    }
  }
#undef STG

  // ---------------- epilogue ----------------
  const int nbase = bn*128 + wn;
  if (ROPE && nbase >= 2048){
    const int b = bm >> 4;
    const int h = (nbase >> 6) & 15;
    #pragma unroll
    for (int ri = 0; ri < 4; ++ri){
      const int m0 = bm*128 + wm + ri*16 + 4*g;
      const int t0 = m0 & (Tz-1);
      #pragma unroll
      for (int cj = 0; cj < 4; ++cj){
        const int d = cj*16 + r;
        u16x4 o;
        #pragma unroll
        for (int jj = 0; jj < 4; ++jj) o[jj] = f2bf(acc[ri][cj][jj]);
        *(u16x4*)(vTout + ((size_t)((b*16 + h)*64 + d))*2048 + t0) = o;
      }
    }
  } else if (ROPE){
    const float qs = (nbase < 1024) ? 0.18033688011112042f : 1.0f;  // 0.125*log2e on q
    #pragma unroll
    for (int ri = 0; ri < 4; ++ri)
      #pragma unroll
      for (int jj = 0; jj < 4; ++jj){
        const int m = bm*128 + wm + ri*16 + 4*g + jj;
        const int t = m & (Tz-1);
        #pragma unroll
        for (int cj = 0; cj < 2; ++cj){
          const int ch = cj*16 + r;
          float cv = cosT[t*32 + ch];
          float sv = sinT[t*32 + ch];
          float lo = acc[ri][cj][jj], hi = acc[ri][cj+2][jj];
          ((u16*)Cout)[(size_t)m*Nn + nbase + ch]      = f2bf((lo*cv - hi*sv)*qs);
          ((u16*)Cout)[(size_t)m*Nn + nbase + ch + 32] = f2bf((hi*cv + lo*sv)*qs);
        }
      }
  } else {
    #pragma unroll
    for (int ri = 0; ri < 4; ++ri)
      #pragma unroll
      for (int cj = 0; cj < 4; ++cj)
        #pragma unroll
        for (int jj = 0; jj < 4; ++jj){
          const size_t m = bm*128 + wm + ri*16 + 4*g + jj;
          const size_t n = (size_t)nbase + cj*16 + r;
          ((float*)Cout)[m*Nn + n] = acc[ri][cj][jj];
        }
  }
}

// ---------------- flash attention v10: 32 q/wave x 8 waves, VGPR cap 128 ----------------
// v9 with the spill bug fixed: __launch_bounds__(512, 2) -> 128-VGPR cap
// (state needs ~95; v9's (512,4) forced 64 and spilled everything).
// LDS-op model: 14 ops/subtile vs v7's 22 -> ~35us target. 2 blocks/CU via
// 69.6KB LDS -> 16 waves/CU. Grid 512 blocks = exactly 2/CU, heavy-first.
__global__ __launch_bounds__(512, 2) void k_attn3(const u16* __restrict__ qkv,
                                                  const u16* __restrict__ vT,
                                                  u16* __restrict__ att){
  extern __shared__ u16 smem[];   // K 2x4096 | V 2x4096 | P 8x32x72  = 69632 B
  u16* K_lds = smem;
  u16* V_lds = smem + 8192;
  u16* P_lds = smem + 16384;

  const int bh = blockIdx.x;
  const int b = bh >> 4, h = bh & 15;
  const int qt2 = 7 - blockIdx.y;      // heavy blocks first
  const int tid = threadIdx.x;
  const int w = tid >> 6;              // 0..7
  const int lane = tid & 63;
  const int g = lane >> 4;
  const int ql = lane & 15;
  u16* Pw = P_lds + w*2304;            // 32 rows x 72 u16 (144 B stride)

  const int srow  = lane >> 3;
  const int sslot = (lane & 7) ^ srow;
  const u16* ksrc = qkv + ((size_t)(b*Tz + 8*w + srow))*3072 + 1024 + h*64 + sslot*8;
  const u16* vsrc = vT  + ((size_t)bh*64 + 8*w + srow)*2048 + sslot*8;
  u16* kdst = K_lds + w*512 + lane*8;
  u16* vdst = V_lds + w*512 + lane*8;

  int fofs[4][2];
  #pragma unroll
  for (int t = 0; t < 4; ++t){
    int row = 16*t + ql;
    fofs[t][0] = (row*128 + 16*g)      ^ ((row & 7) << 4);
    fofs[t][1] = (row*128 + 64 + 16*g) ^ ((row & 7) << 4);
  }

#define STG_KV(kt_, bi_) do{ \
    __builtin_amdgcn_global_load_lds( \
      (const __attribute__((address_space(1))) unsigned int*)(ksrc + (size_t)(kt_)*64*3072), \
      (__attribute__((address_space(3))) unsigned int*)(kdst + (bi_)*4096), 16, 0, 0); \
    __builtin_amdgcn_global_load_lds( \
      (const __attribute__((address_space(1))) unsigned int*)(vsrc + (kt_)*64), \
      (__attribute__((address_space(3))) unsigned int*)(vdst + (bi_)*4096), 16, 0, 0); \
  }while(0)

  const int qr0w = qt2*256 + w*32;     // wave's 32 q-rows
  const int nt = (qt2 + 1)*4;

  const u16* qsrcA = qkv + (size_t)(b*Tz + qr0w + ql)*3072 + h*64;
  const u16* qsrcB = qsrcA + 16*3072;
  short8 qfA0 = *(const short8*)(qsrcA + g*8);
  short8 qfA1 = *(const short8*)(qsrcA + 32 + g*8);
  short8 qfB0 = *(const short8*)(qsrcB + g*8);
  short8 qfB1 = *(const short8*)(qsrcB + 32 + g*8);

  f32x4 accA[4] = {{0,0,0,0},{0,0,0,0},{0,0,0,0},{0,0,0,0}};
  f32x4 accB[4] = {{0,0,0,0},{0,0,0,0},{0,0,0,0},{0,0,0,0}};
  float lrA = 0.0f, lrB = 0.0f;

  STG_KV(0, 0);
  __syncthreads();

  #pragma unroll 2
  for (int kt = 0; kt < nt; ++kt){
    const int buf = kt & 1;
    if (kt + 1 < nt) STG_KV(kt+1, buf^1);
    const char* Kb = (const char*)(K_lds + buf*4096);
    const char* Vb = (const char*)(V_lds + buf*4096);
    const int kv0 = kt*64;

    // QK^T for both subtiles, sharing each K-frag read
    f32x4 stA[4], stB[4];
    __builtin_amdgcn_s_setprio(1);
    #pragma unroll
    for (int t = 0; t < 4; ++t){
      short8 kf0 = *(const short8*)(Kb + fofs[t][0]);
      short8 kf1 = *(const short8*)(Kb + fofs[t][1]);
      f32x4 zA = {0,0,0,0};
      zA = __builtin_amdgcn_mfma_f32_16x16x32_bf16(kf0, qfA0, zA, 0, 0, 0);
      zA = __builtin_amdgcn_mfma_f32_16x16x32_bf16(kf1, qfA1, zA, 0, 0, 0);
      stA[t] = zA;
      f32x4 zB = {0,0,0,0};
      zB = __builtin_amdgcn_mfma_f32_16x16x32_bf16(kf0, qfB0, zB, 0, 0, 0);
      zB = __builtin_amdgcn_mfma_f32_16x16x32_bf16(kf1, qfB1, zB, 0, 0, 0);
      stB[t] = zB;
    }
    __builtin_amdgcn_s_setprio(0);

    // causal masks (wave-uniform branches)
    if (kv0 + 63 > qr0w){
      const int qg = qr0w + ql;
      #pragma unroll
      for (int t = 0; t < 4; ++t)
        #pragma unroll
        for (int j = 0; j < 4; ++j)
          if (kv0 + 16*t + 4*g + j > qg) stA[t][j] = -1e30f;
    }
    if (kv0 + 63 > qr0w + 16){
      const int qg = qr0w + 16 + ql;
      #pragma unroll
      for (int t = 0; t < 4; ++t)
        #pragma unroll
        for (int j = 0; j < 4; ++j)
          if (kv0 + 16*t + 4*g + j > qg) stB[t][j] = -1e30f;
    }

    // p = 2^s; per-lane partial row-sums; pack to P_lds (A rows 0-15, B rows 16-31)
    #pragma unroll
    for (int t = 0; t < 4; ++t){
      float a0, a1, a2, a3, b0, b1, b2, b3;
      asm("v_exp_f32 %0, %1" : "=v"(a0) : "v"(stA[t][0]));
      asm("v_exp_f32 %0, %1" : "=v"(a1) : "v"(stA[t][1]));
      asm("v_exp_f32 %0, %1" : "=v"(a2) : "v"(stA[t][2]));
      asm("v_exp_f32 %0, %1" : "=v"(a3) : "v"(stA[t][3]));
      asm("v_exp_f32 %0, %1" : "=v"(b0) : "v"(stB[t][0]));
      asm("v_exp_f32 %0, %1" : "=v"(b1) : "v"(stB[t][1]));
      asm("v_exp_f32 %0, %1" : "=v"(b2) : "v"(stB[t][2]));
      asm("v_exp_f32 %0, %1" : "=v"(b3) : "v"(stB[t][3]));
      lrA += (a0+a1)+(a2+a3);
      lrB += (b0+b1)+(b2+b3);
      unsigned int wa0, wa1, wb0, wb1;
      asm("v_cvt_pk_bf16_f32 %0, %1, %2" : "=v"(wa0) : "v"(a0), "v"(a1));
      asm("v_cvt_pk_bf16_f32 %0, %1, %2" : "=v"(wa1) : "v"(a2), "v"(a3));
      asm("v_cvt_pk_bf16_f32 %0, %1, %2" : "=v"(wb0) : "v"(b0), "v"(b1));
      asm("v_cvt_pk_bf16_f32 %0, %1, %2" : "=v"(wb1) : "v"(b2), "v"(b3));
      uint2v pva; pva[0] = wa0; pva[1] = wa1;
      uint2v pvb; pvb[0] = wb0; pvb[1] = wb1;
      *(uint2v*)((char*)Pw + ql*144 + (16*t + 4*g)*2) = pva;
      *(uint2v*)((char*)Pw + (16 + ql)*144 + (16*t + 4*g)*2) = pvb;
    }

    short8 pfA0 = *(const short8*)((char*)Pw + ql*144 + 16*g);
    short8 pfA1 = *(const short8*)((char*)Pw + ql*144 + 64 + 16*g);
    short8 pfB0 = *(const short8*)((char*)Pw + (16 + ql)*144 + 16*g);
    short8 pfB1 = *(const short8*)((char*)Pw + (16 + ql)*144 + 64 + 16*g);

    // PV for both subtiles, sharing each V-frag read
    __builtin_amdgcn_s_setprio(1);
    #pragma unroll
    for (int dt = 0; dt < 4; ++dt){
      short8 vf0 = *(const short8*)(Vb + fofs[dt][0]);
      short8 vf1 = *(const short8*)(Vb + fofs[dt][1]);
      accA[dt] = __builtin_amdgcn_mfma_f32_16x16x32_bf16(pfA0, vf0, accA[dt], 0, 0, 0);
      accA[dt] = __builtin_amdgcn_mfma_f32_16x16x32_bf16(pfA1, vf1, accA[dt], 0, 0, 0);
      accB[dt] = __builtin_amdgcn_mfma_f32_16x16x32_bf16(pfB0, vf0, accB[dt], 0, 0, 0);
      accB[dt] = __builtin_amdgcn_mfma_f32_16x16x32_bf16(pfB1, vf1, accB[dt], 0, 0, 0);
    }
    __builtin_amdgcn_s_setprio(0);
    __syncthreads();   // guards dbuf rotation (includes vmcnt drain)
  }
#undef STG_KV

  // denominator reduce once per q-tile
  lrA += __shfl_xor(lrA, 16); lrA += __shfl_xor(lrA, 32);
  lrB += __shfl_xor(lrB, 16); lrB += __shfl_xor(lrB, 32);
  float liA = 1.0f / lrA;
  float liB = 1.0f / lrB;
  float lA0 = __shfl(liA, 4*g+0), lA1 = __shfl(liA, 4*g+1);
  float lA2 = __shfl(liA, 4*g+2), lA3 = __shfl(liA, 4*g+3);
  float lB0 = __shfl(liB, 4*g+0), lB1 = __shfl(liB, 4*g+1);
  float lB2 = __shfl(liB, 4*g+2), lB3 = __shfl(liB, 4*g+3);
  #pragma unroll
  for (int dt = 0; dt < 4; ++dt){
    float ljA[4] = {lA0, lA1, lA2, lA3};
    float ljB[4] = {lB0, lB1, lB2, lB3};
    #pragma unroll
    for (int j = 0; j < 4; ++j){
      att[(size_t)(b*Tz + qr0w + 4*g + j)*Cz + h*64 + dt*16 + ql]      = f2bf(accA[dt][j]*ljA[j]);
      att[(size_t)(b*Tz + qr0w + 16 + 4*g + j)*Cz + h*64 + dt*16 + ql] = f2bf(accB[dt][j]*ljB[j]);
    }
  }
}

// ---------------- launcher ----------------

extern "C" void kernel_launch(void* const* d_in, const int* in_sizes, int n_in,
                              void* d_out, int out_size, void* d_ws, size_t ws_size,
                              hipStream_t stream){
  const float* x     = (const float*)d_in[0];
  const float* Wqkv  = (const float*)d_in[1];
  const float* Wproj = (const float*)d_in[2];
  float* out = (float*)d_out;
  char* ws = (char*)d_ws;

  u16*  xb   = (u16*)(ws);                      // x bf16; reused as attn output
  u16*  wqt  = (u16*)(ws + 16777216);
  u16*  wpt  = (u16*)(ws + 23068672);
  u16*  qkv  = (u16*)(ws + 25165824);           // q,k planes (v diverted to vT)
  u16*  vTr  = (u16*)(ws + 75497472);           // V^T [bh*64+d][2048]
  float* cosT = (float*)(ws + 92274688);
  float* sinT = (float*)(ws + 92536832);

  hipFuncSetAttribute(reinterpret_cast<const void*>(k_attn3),
                      hipFuncAttributeMaxDynamicSharedMemorySize, 69632);

  k_prep<<<12544, 256, 0, stream>>>(x, xb, Wqkv, wqt, Wproj, wpt, cosT, sinT);

  k_gemmdb<3072, 1024, true><<<dim3(Mz/128, 3072/128), 256, 0, stream>>>(
      xb, wqt, qkv, vTr, cosT, sinT);
  k_attn3<<<dim3(Bz*NHz, 8), 512, 69632, stream>>>(qkv, vTr, xb);
  k_gemmdb<1024, 1024, false><<<dim3(Mz/128, 1024/128), 256, 0, stream>>>(
      xb, wpt, out, nullptr, nullptr, nullptr);
}

// Round 17
// 148.662 us; speedup vs baseline: 1.5219x; 1.0308x over previous
//
#include <hip/hip_runtime.h>
#include <stdint.h>

#define Bz 4
#define Tz 2048
#define Cz 1024
#define NHz 16
#define DHz 64
#define Mz (Bz*Tz)

typedef unsigned short u16;
typedef __attribute__((ext_vector_type(8))) short short8;
typedef __attribute__((ext_vector_type(8))) unsigned short ushort8v;
typedef __attribute__((ext_vector_type(4))) unsigned short u16x4;
typedef __attribute__((ext_vector_type(4))) float f32x4;
typedef __attribute__((ext_vector_type(2))) unsigned int uint2v;

__device__ __forceinline__ float bf2f(u16 u){
  union { unsigned int i; float f; } v; v.i = ((unsigned int)u) << 16; return v.f;
}
__device__ __forceinline__ u16 f2bf(float f){
  union { float f; unsigned int i; } v; v.f = f;
  unsigned int r = v.i + 0x7FFFu + ((v.i >> 16) & 1u);
  return (u16)(r >> 16);
}

// ---------------- fused pre-pass ----------------
__global__ void k_prep(const float* __restrict__ x,     u16* __restrict__ xb,
                       const float* __restrict__ Wqkv,  u16* __restrict__ wqt,
                       const float* __restrict__ Wproj, u16* __restrict__ wpt,
                       float* __restrict__ cosT, float* __restrict__ sinT){
  __shared__ float tile[32][33];
  const int blk = blockIdx.x;
  const int tid = threadIdx.x;
  if (blk < 8192){
    int i = blk*256 + tid;
    float4 v = ((const float4*)x)[i];
    u16x4 o;
    o[0] = f2bf(v.x); o[1] = f2bf(v.y); o[2] = f2bf(v.z); o[3] = f2bf(v.w);
    *(u16x4*)(xb + (size_t)i*4) = o;
  } else if (blk < 12288){
    const float* W; u16* Wt; int K, N, bx, by;
    if (blk < 11264){ int b2 = blk - 8192;  W = Wqkv;  Wt = wqt; K = 1024; N = 3072; bx = b2 % 96; by = b2 / 96; }
    else            { int b2 = blk - 11264; W = Wproj; Wt = wpt; K = 1024; N = 1024; bx = b2 % 32; by = b2 / 32; }
    const int n0 = bx*32, k0 = by*32;
    const int tx = tid & 31, ty = tid >> 5;
    #pragma unroll
    for (int i = 0; i < 32; i += 8)
      tile[ty+i][tx] = W[(size_t)(k0+ty+i)*N + n0 + tx];
    __syncthreads();
    #pragma unroll
    for (int i = 0; i < 32; i += 8)
      Wt[(size_t)(n0+ty+i)*K + k0 + tx] = f2bf(tile[tx][ty+i]);
  } else {
    int idx = (blk - 12288)*256 + tid;      // 2048*32 entries
    int t = idx >> 5, i = idx & 31;
    float theta = exp2f(-(float)i * (13.287712379549449f / 32.0f)); // 10000^(-i/32)
    float ang = (float)t * theta;
    cosT[idx] = cosf(ang);
    sinT[idx] = sinf(ang);
  }
}

// ---------------- GEMM: 128x128, BK=64, 4 waves of 64x64, double-buffered ----------------
#define GLDS(src, dstE) __builtin_amdgcn_global_load_lds( \
    (const __attribute__((address_space(1))) unsigned int*)(src), \
    (__attribute__((address_space(3))) unsigned int*)((u16*)lds + (dstE)), 16, 0, 0)

template<int Nn, int Kk, bool ROPE>
__global__ __launch_bounds__(256, 4) void k_gemmdb(const u16* __restrict__ A, const u16* __restrict__ Bt,
                        void* __restrict__ Cout, u16* __restrict__ vTout,
                        const float* __restrict__ cosT, const float* __restrict__ sinT){
  __shared__ u16 lds[2][16384];           // [buf][ A 128x64 | B 128x64 ]  = 64 KB
  constexpr int NT = Kk/64;
  const int bm = blockIdx.x, bn = blockIdx.y;
  const int tid = threadIdx.x, lane = tid & 63, w = tid >> 6;
  const int wm = (w >> 1)*64, wn = (w & 1)*64;
  const int g = lane >> 4, r = lane & 15;

  const int srow8 = lane >> 3;
  const int sslot = (lane & 7) ^ srow8;   // pre-swizzled source slot (involution)
  const u16* asrc = A  + (size_t)(bm*128 + w*32 + srow8)*Kk + sslot*8;
  const u16* bsrc = Bt + (size_t)(bn*128 + w*32 + srow8)*Kk + sslot*8;
  const int dA = w*2048 + lane*8;
  const int dB = 8192 + w*2048 + lane*8;

  int a_off[4][2], b_off[4][2];
  #pragma unroll
  for (int i = 0; i < 4; ++i)
    #pragma unroll
    for (int kc = 0; kc < 2; ++kc){
      int row = wm + i*16 + r;
      a_off[i][kc] = (row*128 + kc*64 + g*16) ^ ((r & 7) << 4);
      int rowb = wn + i*16 + r;
      b_off[i][kc] = 16384 + ((rowb*128 + kc*64 + g*16) ^ ((r & 7) << 4));
    }

  f32x4 acc[4][4] = {};

#define STG(t, bi) do{ \
    const size_t ko_ = (size_t)(t)*64; \
    const int be_ = (bi)*16384; \
    GLDS(asrc + ko_,                 be_ + dA);        \
    GLDS(asrc + ko_ +  8*(size_t)Kk, be_ + dA + 512);  \
    GLDS(asrc + ko_ + 16*(size_t)Kk, be_ + dA + 1024); \
    GLDS(asrc + ko_ + 24*(size_t)Kk, be_ + dA + 1536); \
    GLDS(bsrc + ko_,                 be_ + dB);        \
    GLDS(bsrc + ko_ +  8*(size_t)Kk, be_ + dB + 512);  \
    GLDS(bsrc + ko_ + 16*(size_t)Kk, be_ + dB + 1024); \
    GLDS(bsrc + ko_ + 24*(size_t)Kk, be_ + dB + 1536); \
  }while(0)

  STG(0, 0);
  asm volatile("s_waitcnt vmcnt(0)" ::: "memory");
  __builtin_amdgcn_s_barrier();

  int buf = 0;
  #pragma unroll 1
  for (int t = 0; t < NT; ++t){
    if (t + 1 < NT) STG(t+1, buf^1);
    const char* Lb = (const char*)lds + buf*32768;
    short8 af[4][2], bf[4][2];
    #pragma unroll
    for (int i = 0; i < 4; ++i)
      #pragma unroll
      for (int kc = 0; kc < 2; ++kc){
        af[i][kc] = *(const short8*)(Lb + a_off[i][kc]);
        bf[i][kc] = *(const short8*)(Lb + b_off[i][kc]);
      }
    __builtin_amdgcn_s_setprio(1);
    #pragma unroll
    for (int i = 0; i < 4; ++i)
      #pragma unroll
      for (int j = 0; j < 4; ++j){
        acc[i][j] = __builtin_amdgcn_mfma_f32_16x16x32_bf16(af[i][0], bf[j][0], acc[i][j], 0,0,0);
        acc[i][j] = __builtin_amdgcn_mfma_f32_16x16x32_bf16(af[i][1], bf[j][1], acc[i][j], 0,0,0);
      }
    __builtin_amdgcn_s_setprio(0);
    if (t + 1 < NT){
      asm volatile("s_waitcnt vmcnt(0)" ::: "memory");
      __builtin_amdgcn_s_barrier();
      buf ^= 1;
    }
  }
#undef STG

  // ---------------- epilogue ----------------
  const int nbase = bn*128 + wn;
  if (ROPE && nbase >= 2048){
    const int b = bm >> 4;
    const int h = (nbase >> 6) & 15;
    #pragma unroll
    for (int ri = 0; ri < 4; ++ri){
      const int m0 = bm*128 + wm + ri*16 + 4*g;
      const int t0 = m0 & (Tz-1);
      #pragma unroll
      for (int cj = 0; cj < 4; ++cj){
        const int d = cj*16 + r;
        u16x4 o;
        #pragma unroll
        for (int jj = 0; jj < 4; ++jj) o[jj] = f2bf(acc[ri][cj][jj]);
        *(u16x4*)(vTout + ((size_t)((b*16 + h)*64 + d))*2048 + t0) = o;
      }
    }
  } else if (ROPE){
    const float qs = (nbase < 1024) ? 0.18033688011112042f : 1.0f;  // 0.125*log2e on q
    #pragma unroll
    for (int ri = 0; ri < 4; ++ri)
      #pragma unroll
      for (int jj = 0; jj < 4; ++jj){
        const int m = bm*128 + wm + ri*16 + 4*g + jj;
        const int t = m & (Tz-1);
        #pragma unroll
        for (int cj = 0; cj < 2; ++cj){
          const int ch = cj*16 + r;
          float cv = cosT[t*32 + ch];
          float sv = sinT[t*32 + ch];
          float lo = acc[ri][cj][jj], hi = acc[ri][cj+2][jj];
          ((u16*)Cout)[(size_t)m*Nn + nbase + ch]      = f2bf((lo*cv - hi*sv)*qs);
          ((u16*)Cout)[(size_t)m*Nn + nbase + ch + 32] = f2bf((hi*cv + lo*sv)*qs);
        }
      }
  } else {
    #pragma unroll
    for (int ri = 0; ri < 4; ++ri)
      #pragma unroll
      for (int cj = 0; cj < 4; ++cj)
        #pragma unroll
        for (int jj = 0; jj < 4; ++jj){
          const size_t m = bm*128 + wm + ri*16 + 4*g + jj;
          const size_t n = (size_t)nbase + cj*16 + r;
          ((float*)Cout)[m*Nn + n] = acc[ri][cj][jj];
        }
  }
}

// ---------------- flash attention v7 ----------------
// 8 waves x 16 q = 128 q/block; dbuf K/V via global_load_lds; ones-MFMA
// denominator; direct exp2 (log2-domain scores); unpaired grid (64 bh, 16 qt)
// heavy-first -> 1024 blocks = 3 blocks/CU (24 waves/CU).
__global__ __launch_bounds__(512) void k_attn2(const u16* __restrict__ qkv,
                                               const u16* __restrict__ vT,
                                               u16* __restrict__ att){
  __shared__ u16 K_lds[2*4096];
  __shared__ u16 V_lds[2*4096];
  __shared__ u16 P_lds[8*16*72];

  const int bh = blockIdx.x;           // bh fastest -> K/V L2 locality per XCD
  const int b = bh >> 4, h = bh & 15;
  const int qt = 15 - blockIdx.y;      // heavy blocks first
  const int tid = threadIdx.x;
  const int w = tid >> 6;
  const int lane = tid & 63;
  const int g = lane >> 4;
  const int ql = lane & 15;
  u16* Pw = P_lds + w*16*72;

  const int srow  = lane >> 3;
  const int sslot = (lane & 7) ^ srow;
  const u16* ksrc = qkv + ((size_t)(b*Tz + 8*w + srow))*3072 + 1024 + h*64 + sslot*8;
  const u16* vsrc = vT  + ((size_t)bh*64 + 8*w + srow)*2048 + sslot*8;
  u16* kdst = K_lds + w*512 + lane*8;
  u16* vdst = V_lds + w*512 + lane*8;

  short8 ones;
  #pragma unroll
  for (int i = 0; i < 8; ++i) ones[i] = (short)0x3F80;   // bf16 1.0

  int fofs[4][2];
  #pragma unroll
  for (int t = 0; t < 4; ++t){
    int row = 16*t + ql;
    fofs[t][0] = (row*128 + 16*g)      ^ ((row & 7) << 4);
    fofs[t][1] = (row*128 + 64 + 16*g) ^ ((row & 7) << 4);
  }

  const int qr0w = qt*128 + w*16;
  const int nt = 2*qt + 2;

  const u16* qsrc = qkv + (size_t)(b*Tz + qr0w + ql)*3072 + h*64;
  short8 qf0 = *(const short8*)(qsrc + g*8);
  short8 qf1 = *(const short8*)(qsrc + 32 + g*8);

  f32x4 acc[4] = {{0,0,0,0},{0,0,0,0},{0,0,0,0},{0,0,0,0}};
  f32x4 accl = {0,0,0,0};   // row-sum of P via ones-MFMA

  __builtin_amdgcn_global_load_lds(
    (const __attribute__((address_space(1))) unsigned int*)(ksrc),
    (__attribute__((address_space(3))) unsigned int*)(kdst), 16, 0, 0);
  __builtin_amdgcn_global_load_lds(
    (const __attribute__((address_space(1))) unsigned int*)(vsrc),
    (__attribute__((address_space(3))) unsigned int*)(vdst), 16, 0, 0);
  __syncthreads();

  #pragma unroll 2
  for (int kt = 0; kt < nt; ++kt){
    const int buf = kt & 1;
    if (kt + 1 < nt){
      __builtin_amdgcn_global_load_lds(
        (const __attribute__((address_space(1))) unsigned int*)(ksrc + (size_t)(kt+1)*64*3072),
        (__attribute__((address_space(3))) unsigned int*)(kdst + (buf^1)*4096), 16, 0, 0);
      __builtin_amdgcn_global_load_lds(
        (const __attribute__((address_space(1))) unsigned int*)(vsrc + (kt+1)*64),
        (__attribute__((address_space(3))) unsigned int*)(vdst + (buf^1)*4096), 16, 0, 0);
    }
    const char* Kb = (const char*)(K_lds + buf*4096);
    const char* Vb = (const char*)(V_lds + buf*4096);
    const int kv0 = kt*64;

    f32x4 st[4];
    __builtin_amdgcn_s_setprio(1);
    #pragma unroll
    for (int t = 0; t < 4; ++t){
      short8 kf0 = *(const short8*)(Kb + fofs[t][0]);
      short8 kf1 = *(const short8*)(Kb + fofs[t][1]);
      f32x4 z = {0,0,0,0};
      z = __builtin_amdgcn_mfma_f32_16x16x32_bf16(kf0, qf0, z, 0, 0, 0);
      z = __builtin_amdgcn_mfma_f32_16x16x32_bf16(kf1, qf1, z, 0, 0, 0);
      st[t] = z;
    }
    __builtin_amdgcn_s_setprio(0);

    if (kv0 + 63 > qr0w){
      const int qg = qr0w + ql;
      #pragma unroll
      for (int t = 0; t < 4; ++t)
        #pragma unroll
        for (int j = 0; j < 4; ++j)
          if (kv0 + 16*t + 4*g + j > qg) st[t][j] = -1e30f;
    }

    #pragma unroll
    for (int t = 0; t < 4; ++t){
      float p0, p1, p2, p3;
      asm("v_exp_f32 %0, %1" : "=v"(p0) : "v"(st[t][0]));
      asm("v_exp_f32 %0, %1" : "=v"(p1) : "v"(st[t][1]));
      asm("v_exp_f32 %0, %1" : "=v"(p2) : "v"(st[t][2]));
      asm("v_exp_f32 %0, %1" : "=v"(p3) : "v"(st[t][3]));
      unsigned int lov, hiv;
      asm("v_cvt_pk_bf16_f32 %0, %1, %2" : "=v"(lov) : "v"(p0), "v"(p1));
      asm("v_cvt_pk_bf16_f32 %0, %1, %2" : "=v"(hiv) : "v"(p2), "v"(p3));
      uint2v pv; pv[0] = lov; pv[1] = hiv;
      *(uint2v*)((char*)Pw + ql*144 + (16*t + 4*g)*2) = pv;
    }

    short8 pf0 = *(const short8*)((char*)Pw + ql*144 + 16*g);
    short8 pf1 = *(const short8*)((char*)Pw + ql*144 + 64 + 16*g);
    __builtin_amdgcn_s_setprio(1);
    accl = __builtin_amdgcn_mfma_f32_16x16x32_bf16(pf0, ones, accl, 0, 0, 0);
    accl = __builtin_amdgcn_mfma_f32_16x16x32_bf16(pf1, ones, accl, 0, 0, 0);
    #pragma unroll
    for (int dt = 0; dt < 4; ++dt){
      short8 vf0 = *(const short8*)(Vb + fofs[dt][0]);
      short8 vf1 = *(const short8*)(Vb + fofs[dt][1]);
      acc[dt] = __builtin_amdgcn_mfma_f32_16x16x32_bf16(pf0, vf0, acc[dt], 0, 0, 0);
      acc[dt] = __builtin_amdgcn_mfma_f32_16x16x32_bf16(pf1, vf1, acc[dt], 0, 0, 0);
    }
    __builtin_amdgcn_s_setprio(0);
    __syncthreads();
  }

  float lj[4];
  #pragma unroll
  for (int j = 0; j < 4; ++j) lj[j] = 1.0f / accl[j];
  #pragma unroll
  for (int dt = 0; dt < 4; ++dt)
    #pragma unroll
    for (int j = 0; j < 4; ++j)
      att[(size_t)(b*Tz + qr0w + 4*g + j)*Cz + h*64 + dt*16 + ql] = f2bf(acc[dt][j]*lj[j]);
}

// ---------------- launcher ----------------

extern "C" void kernel_launch(void* const* d_in, const int* in_sizes, int n_in,
                              void* d_out, int out_size, void* d_ws, size_t ws_size,
                              hipStream_t stream){
  const float* x     = (const float*)d_in[0];
  const float* Wqkv  = (const float*)d_in[1];
  const float* Wproj = (const float*)d_in[2];
  float* out = (float*)d_out;
  char* ws = (char*)d_ws;

  u16*  xb   = (u16*)(ws);                      // x bf16; reused as attn output
  u16*  wqt  = (u16*)(ws + 16777216);
  u16*  wpt  = (u16*)(ws + 23068672);
  u16*  qkv  = (u16*)(ws + 25165824);           // q,k planes (v diverted to vT)
  u16*  vTr  = (u16*)(ws + 75497472);           // V^T [bh*64+d][2048]
  float* cosT = (float*)(ws + 92274688);
  float* sinT = (float*)(ws + 92536832);

  k_prep<<<12544, 256, 0, stream>>>(x, xb, Wqkv, wqt, Wproj, wpt, cosT, sinT);

  k_gemmdb<3072, 1024, true><<<dim3(Mz/128, 3072/128), 256, 0, stream>>>(
      xb, wqt, qkv, vTr, cosT, sinT);
  k_attn2<<<dim3(Bz*NHz, 16), 512, 0, stream>>>(qkv, vTr, xb);
  k_gemmdb<1024, 1024, false><<<dim3(Mz/128, 1024/128), 256, 0, stream>>>(
      xb, wpt, out, nullptr, nullptr, nullptr);
}